// Round 14
// baseline (171.099 us; speedup 1.0000x reference)
//
#include <hip/hip_runtime.h>
#include <hip/hip_bf16.h>

#define EPSF 1e-7f

typedef __attribute__((ext_vector_type(8))) short bf16x8;
typedef __attribute__((ext_vector_type(4))) float f32x4v;

__device__ inline ushort f2bf_bits(float x) {
    union { __hip_bfloat16 b; ushort u; } cv;
    cv.b = __float2bfloat16(x);
    return cv.u;
}
__device__ inline float bfbits2f(ushort u) {
    union { ushort u; __hip_bfloat16 b; } cv;
    cv.u = u;
    return __bfloat162float(cv.b);
}
__device__ inline void split2(float x, ushort& h, ushort& l) {
    h = f2bf_bits(x);
    l = f2bf_bits(x - bfbits2f(h));
}
__device__ inline uint4 pack8(const ushort* h) {
    uint4 p;
    p.x = (uint)h[0] | ((uint)h[1] << 16);
    p.y = (uint)h[2] | ((uint)h[3] << 16);
    p.z = (uint)h[4] | ((uint)h[5] << 16);
    p.w = (uint)h[6] | ((uint)h[7] << 16);
    return p;
}

__device__ inline void gload_lds16(const ushort* g, ushort* l) {
    __builtin_amdgcn_global_load_lds(
        (const __attribute__((address_space(1))) unsigned int*)g,
        (__attribute__((address_space(3))) unsigned int*)l, 16, 0, 0);
}

// ---------------- csq + C -> Chl + zero sum_w/rsum ----------------
__global__ __launch_bounds__(256) void csqc_v3(const float* __restrict__ C,
                                               float* __restrict__ csq,
                                               ushort* __restrict__ Chl,
                                               float* __restrict__ sum_w,
                                               float* __restrict__ rsum) {
    const int wave = threadIdx.x >> 6, lane = threadIdx.x & 63;
    const int row = blockIdx.x * 4 + wave;
    const int kc = lane >> 2, s = lane & 3;
    if (blockIdx.x == 0) {   // fold the old hipMemsetAsync
        sum_w[threadIdx.x] = 0.f;
        sum_w[256 + threadIdx.x] = 0.f;
        rsum[threadIdx.x] = 0.f;
        rsum[256 + threadIdx.x] = 0.f;
    }
    const float* p = C + row * 512 + lane * 8;
    float4 a = *(const float4*)p;
    float4 b = *(const float4*)(p + 4);
    float v[8] = {a.x, a.y, a.z, a.w, b.x, b.y, b.z, b.w};
    ushort h[8], l[8];
    float sqs = 0.f;
#pragma unroll
    for (int i = 0; i < 8; ++i) {
        sqs += v[i] * v[i];
        split2(v[i], h[i], l[i]);
    }
    ushort* base = Chl + (long)row * 1024 + kc * 64 + s * 8;
    *(uint4*)base = pack8(h);
    *(uint4*)(base + 32) = pack8(l);
#pragma unroll
    for (int off = 1; off < 64; off <<= 1) sqs += __shfl_xor(sqs, off, 64);
    if (lane == 0) csq[row] = sqs;
}

// ---------------- logsm: fused X-convert + logits GEMM + row softmax ----------------
// X-prefetch for kc+1 issued AFTER the pre-MFMA barrier (flies during MFMA phase,
// drained at next loop-top barrier). R12 had it before the barrier -> vmcnt(0) killed it.
__global__ __launch_bounds__(512) void logsm(const float* __restrict__ X,
                                             const ushort* __restrict__ Chl,
                                             const float* __restrict__ csq,
                                             float* __restrict__ assign,
                                             ushort* __restrict__ Abf,
                                             ushort* __restrict__ Xh,
                                             float* __restrict__ sum_w) {
    __shared__ __align__(16) ushort sA[64 * 64];      // 8 KB (hi|lo per kc)
    __shared__ __align__(16) ushort sB[512 * 64];     // 64 KB
    __shared__ float rmaxs[64][4];
    __shared__ float rsums[64][4];
    __shared__ float swacc[512];
    const int tid = threadIdx.x;
    const int m0 = ((blockIdx.x & 7) * 64 + (blockIdx.x >> 3)) * 64;
    const int wid = tid >> 6, lane = tid & 63;
    const int wm = wid >> 2, wn = wid & 3;
    const int lrow = lane & 15, lkb = lane >> 4;
    swacc[tid] = 0.f;
    f32x4v acc[2][8] = {};

    const int ar = tid >> 3, aq = tid & 7;   // A-stage task: row 0..63, quad 0..7
    const float* xrow = X + (long)(m0 + ar) * 512 + aq * 4;
    float4 v = *(const float4*)xrow;         // prefetch kc=0 (exposed once)

#pragma unroll 1
    for (int kc = 0; kc < 16; ++kc) {
        __syncthreads();
        {   // A: split prefetched quad, ds_write swizzled; write Xh byproduct
            ushort h[4], l[4];
            split2(v.x, h[0], l[0]);
            split2(v.y, h[1], l[1]);
            split2(v.z, h[2], l[2]);
            split2(v.w, h[3], l[3]);
            ushort4 hv = {h[0], h[1], h[2], h[3]};
            ushort4 lv = {l[0], l[1], l[2], l[3]};
            const int sh = (aq >> 1) ^ (ar & 7);
            const int slo = ((aq >> 1) + 4) ^ (ar & 7);
            *(ushort4*)&sA[ar * 64 + (sh << 3) + (aq & 1) * 4] = hv;
            *(ushort4*)&sA[ar * 64 + (slo << 3) + (aq & 1) * 4] = lv;
            *(ushort4*)(Xh + (long)(m0 + ar) * 512 + kc * 32 + aq * 4) = hv;
        }
#pragma unroll
        for (int i = 0; i < 8; ++i) {   // B: 512 rows = 4096 slots, 8/thread
            const int sl = i * 512 + tid;
            const int r = sl >> 3, j = sl & 7;
            const int s = j ^ (r & 7);
            gload_lds16(Chl + (long)r * 1024 + kc * 64 + s * 8,
                        &sB[(i * 512 + wid * 64) * 8]);
        }
        __syncthreads();
        if (kc < 15) v = *(const float4*)(xrow + (kc + 1) * 32);  // issue in MFMA phase
        bf16x8 ah[2], al[2];
#pragma unroll
        for (int mi = 0; mi < 2; ++mi) {
            const int R = wm * 32 + mi * 16 + lrow;
            ah[mi] = *(const bf16x8*)&sA[R * 64 + ((lkb ^ (R & 7)) << 3)];
            al[mi] = *(const bf16x8*)&sA[R * 64 + (((lkb + 4) ^ (R & 7)) << 3)];
        }
        __builtin_amdgcn_s_setprio(1);
#pragma unroll
        for (int ni = 0; ni < 8; ++ni) {
            const int Rn = wn * 128 + ni * 16 + lrow;
            bf16x8 bh = *(const bf16x8*)&sB[Rn * 64 + ((lkb ^ (Rn & 7)) << 3)];
            bf16x8 bl = *(const bf16x8*)&sB[Rn * 64 + (((lkb + 4) ^ (Rn & 7)) << 3)];
#pragma unroll
            for (int mi = 0; mi < 2; ++mi) {
                acc[mi][ni] = __builtin_amdgcn_mfma_f32_16x16x32_bf16(ah[mi], bh, acc[mi][ni], 0, 0, 0);
                acc[mi][ni] = __builtin_amdgcn_mfma_f32_16x16x32_bf16(ah[mi], bl, acc[mi][ni], 0, 0, 0);
                acc[mi][ni] = __builtin_amdgcn_mfma_f32_16x16x32_bf16(al[mi], bh, acc[mi][ni], 0, 0, 0);
            }
        }
        __builtin_amdgcn_s_setprio(0);
    }
    // ---- epilogue: logits -> softmax -> outputs ----
    const int colb = wn * 128 + lrow;
    float cs[8];
#pragma unroll
    for (int ni = 0; ni < 8; ++ni) cs[ni] = csq[colb + ni * 16];
    float mx[2][4];
#pragma unroll
    for (int mi = 0; mi < 2; ++mi)
#pragma unroll
        for (int r = 0; r < 4; ++r) {
            float m = -3.0e38f;
#pragma unroll
            for (int ni = 0; ni < 8; ++ni) {
                float l = 2.0f * acc[mi][ni][r] - cs[ni];
                acc[mi][ni][r] = l;
                m = fmaxf(m, l);
            }
            mx[mi][r] = m;
        }
#pragma unroll
    for (int off = 1; off < 16; off <<= 1)
#pragma unroll
        for (int mi = 0; mi < 2; ++mi)
#pragma unroll
            for (int r = 0; r < 4; ++r) mx[mi][r] = fmaxf(mx[mi][r], __shfl_xor(mx[mi][r], off, 64));
    if (lrow == 0) {
#pragma unroll
        for (int mi = 0; mi < 2; ++mi)
#pragma unroll
            for (int r = 0; r < 4; ++r) rmaxs[wm * 32 + mi * 16 + lkb * 4 + r][wn] = mx[mi][r];
    }
    __syncthreads();
    float gmax[2][4];
#pragma unroll
    for (int mi = 0; mi < 2; ++mi)
#pragma unroll
        for (int r = 0; r < 4; ++r) {
            const int row = wm * 32 + mi * 16 + lkb * 4 + r;
            gmax[mi][r] = fmaxf(fmaxf(rmaxs[row][0], rmaxs[row][1]),
                                fmaxf(rmaxs[row][2], rmaxs[row][3]));
        }
    float sm[2][4] = {};
#pragma unroll
    for (int mi = 0; mi < 2; ++mi)
#pragma unroll
        for (int ni = 0; ni < 8; ++ni)
#pragma unroll
            for (int r = 0; r < 4; ++r) {
                float e = expf((acc[mi][ni][r] - gmax[mi][r]) * 10.0f);
                acc[mi][ni][r] = e;
                sm[mi][r] += e;
            }
#pragma unroll
    for (int off = 1; off < 16; off <<= 1)
#pragma unroll
        for (int mi = 0; mi < 2; ++mi)
#pragma unroll
            for (int r = 0; r < 4; ++r) sm[mi][r] += __shfl_xor(sm[mi][r], off, 64);
    if (lrow == 0) {
#pragma unroll
        for (int mi = 0; mi < 2; ++mi)
#pragma unroll
            for (int r = 0; r < 4; ++r) rsums[wm * 32 + mi * 16 + lkb * 4 + r][wn] = sm[mi][r];
    }
    __syncthreads();
    float inv[2][4];
#pragma unroll
    for (int mi = 0; mi < 2; ++mi)
#pragma unroll
        for (int r = 0; r < 4; ++r) {
            const int row = wm * 32 + mi * 16 + lkb * 4 + r;
            float t = rsums[row][0] + rsums[row][1] + rsums[row][2] + rsums[row][3];
            inv[mi][r] = 1.0f / (t + EPSF);
        }
    float csum[8] = {};
#pragma unroll
    for (int mi = 0; mi < 2; ++mi)
#pragma unroll
        for (int ni = 0; ni < 8; ++ni) {
            const int col = colb + ni * 16;
#pragma unroll
            for (int r = 0; r < 4; ++r) {
                const int row = wm * 32 + mi * 16 + lkb * 4 + r;
                float a = acc[mi][ni][r] * inv[mi][r];
                assign[(long)(m0 + row) * 512 + col] = a;
                Abf[(long)(m0 + row) * 512 + col] = f2bf_bits(a);
                csum[ni] += a;
            }
        }
#pragma unroll
    for (int off = 16; off < 64; off <<= 1)
#pragma unroll
        for (int ni = 0; ni < 8; ++ni) csum[ni] += __shfl_xor(csum[ni], off, 64);
    if (lkb == 0) {
#pragma unroll
        for (int ni = 0; ni < 8; ++ni) atomicAdd(&swacc[colb + ni * 16], csum[ni]);
    }
    __syncthreads();
    atomicAdd(&sum_w[tid], swacc[tid]);
}

// ---------------- wsum (dbuf) + gram merged: blocks 0..511 wsum, 512..527 gram ----------------
__global__ __launch_bounds__(256) void wsum_gram(const ushort* __restrict__ Abf,
                                                 const ushort* __restrict__ Xh,
                                                 float* __restrict__ WSp,
                                                 const ushort* __restrict__ Chl,
                                                 const float* __restrict__ csq,
                                                 float* __restrict__ S,
                                                 float* __restrict__ rsum) {
    __shared__ __align__(16) ushort sA[2][128 * 64];   // 2 x 16 KB
    __shared__ __align__(16) ushort sB[2][128 * 64];
    __shared__ float rs_s[128];
    const int tid = threadIdx.x;
    const int bid = blockIdx.x;
    const int wid = tid >> 6, lane = tid & 63;
    const int wm = wid >> 1, wn = wid & 1;
    const int lrow = lane & 15, lkb = lane >> 4;
    f32x4v acc[4][4] = {};

    if (bid < 512) {
        const int T = (bid & 7) * 64 + (bid >> 3);
        const int k0 = (T & 3) * 128;
        const int d0 = ((T >> 2) & 3) * 128;
        const int zc = T >> 4;                 // 0..31
        const long n0 = (long)zc * 1024;
        ushort ha[4][8], hx[4][8];

#define WSUM_LOAD(NCOFF)                                                      \
        {                                                                      \
            _Pragma("unroll")                                                  \
            for (int it = 0; it < 4; ++it) {                                   \
                const int idx = it * 256 + tid;                                \
                const int c = idx & 127;                                       \
                const int no = idx >> 7;                                       \
                const long nb = n0 + (NCOFF) + (long)no * 8;                   \
                _Pragma("unroll")                                              \
                for (int jj = 0; jj < 8; ++jj) {                               \
                    ha[it][jj] = Abf[(nb + jj) * 512 + k0 + c];                \
                    hx[it][jj] = Xh[(nb + jj) * 512 + d0 + c];                 \
                }                                                              \
            }                                                                  \
        }
#define WSUM_WRITE(B)                                                         \
        {                                                                      \
            _Pragma("unroll")                                                  \
            for (int it = 0; it < 4; ++it) {                                   \
                const int idx = it * 256 + tid;                                \
                const int c = idx & 127;                                       \
                const int no = idx >> 7;                                       \
                const int sl = no ^ (c & 7);                                   \
                *(uint4*)&sA[(B)][c * 64 + sl * 8] = pack8(ha[it]);            \
                *(uint4*)&sB[(B)][c * 64 + sl * 8] = pack8(hx[it]);            \
            }                                                                  \
        }

        WSUM_LOAD(0);
        WSUM_WRITE(0);
        int cur = 0;
#pragma unroll 1
        for (int nc = 0; nc < 16; ++nc) {
            if (nc < 15) WSUM_LOAD((nc + 1) * 64);
            __syncthreads();
            __builtin_amdgcn_s_setprio(1);
#pragma unroll
            for (int kk = 0; kk < 2; ++kk) {
                const int j = kk * 4 + lkb;
                bf16x8 af[4], bfv[4];
#pragma unroll
                for (int mi = 0; mi < 4; ++mi) {
                    const int R = wm * 64 + mi * 16 + lrow;
                    af[mi] = *(const bf16x8*)&sA[cur][R * 64 + ((j ^ (R & 7)) << 3)];
                }
#pragma unroll
                for (int ni = 0; ni < 4; ++ni) {
                    const int R = wn * 64 + ni * 16 + lrow;
                    bfv[ni] = *(const bf16x8*)&sB[cur][R * 64 + ((j ^ (R & 7)) << 3)];
                }
#pragma unroll
                for (int mi = 0; mi < 4; ++mi)
#pragma unroll
                    for (int ni = 0; ni < 4; ++ni)
                        acc[mi][ni] = __builtin_amdgcn_mfma_f32_16x16x32_bf16(af[mi], bfv[ni], acc[mi][ni], 0, 0, 0);
            }
            __builtin_amdgcn_s_setprio(0);
            if (nc < 15) WSUM_WRITE(cur ^ 1);
            cur ^= 1;
        }
        float* dst = WSp + (size_t)zc * 262144;
#pragma unroll
        for (int mi = 0; mi < 4; ++mi) {
            const int k = k0 + wm * 64 + mi * 16 + lkb * 4;
#pragma unroll
            for (int ni = 0; ni < 4; ++ni) {
                const int d = d0 + wn * 64 + ni * 16 + lrow;
#pragma unroll
                for (int r = 0; r < 4; ++r)
                    dst[(k + r) * 512 + d] = acc[mi][ni][r];
            }
        }
#undef WSUM_LOAD
#undef WSUM_WRITE
    } else {
        const int g = bid - 512;               // 0..15
        const int n0 = (g & 3) * 128;
        const int m0 = (g >> 2) * 128;
#pragma unroll 1
        for (int kc = 0; kc < 16; ++kc) {
            __syncthreads();
#pragma unroll
            for (int i = 0; i < 4; ++i) {
                const int sl = wid * 256 + i * 64 + lane;
                const int r = sl >> 3, j = sl & 7;
                const int s = j ^ (r & 7);
                gload_lds16(Chl + (long)(m0 + r) * 1024 + kc * 64 + s * 8,
                            &sA[0][(wid * 256 + i * 64) * 8]);
                gload_lds16(Chl + (long)(n0 + r) * 1024 + kc * 64 + s * 8,
                            &sB[0][(wid * 256 + i * 64) * 8]);
            }
            __syncthreads();
            bf16x8 ah[4], al[4], bh[4], bl[4];
#pragma unroll
            for (int mi = 0; mi < 4; ++mi) {
                const int R = wm * 64 + mi * 16 + lrow;
                ah[mi] = *(const bf16x8*)&sA[0][R * 64 + ((lkb ^ (R & 7)) << 3)];
                al[mi] = *(const bf16x8*)&sA[0][R * 64 + (((lkb + 4) ^ (R & 7)) << 3)];
            }
#pragma unroll
            for (int ni = 0; ni < 4; ++ni) {
                const int R = wn * 64 + ni * 16 + lrow;
                bh[ni] = *(const bf16x8*)&sB[0][R * 64 + ((lkb ^ (R & 7)) << 3)];
                bl[ni] = *(const bf16x8*)&sB[0][R * 64 + (((lkb + 4) ^ (R & 7)) << 3)];
            }
            __builtin_amdgcn_s_setprio(1);
#pragma unroll
            for (int mi = 0; mi < 4; ++mi)
#pragma unroll
                for (int ni = 0; ni < 4; ++ni) {
                    acc[mi][ni] = __builtin_amdgcn_mfma_f32_16x16x32_bf16(ah[mi], bh[ni], acc[mi][ni], 0, 0, 0);
                    acc[mi][ni] = __builtin_amdgcn_mfma_f32_16x16x32_bf16(ah[mi], bl[ni], acc[mi][ni], 0, 0, 0);
                    acc[mi][ni] = __builtin_amdgcn_mfma_f32_16x16x32_bf16(al[mi], bh[ni], acc[mi][ni], 0, 0, 0);
                }
            __builtin_amdgcn_s_setprio(0);
        }
        if (tid < 128) rs_s[tid] = 0.f;
        __syncthreads();
        const int colb = n0 + wn * 64 + lrow;
        float csj[4];
#pragma unroll
        for (int ni = 0; ni < 4; ++ni) csj[ni] = csq[colb + ni * 16];
#pragma unroll
        for (int mi = 0; mi < 4; ++mi) {
            const int rowb = m0 + wm * 64 + mi * 16 + lkb * 4;
#pragma unroll
            for (int r = 0; r < 4; ++r) {
                const int row = rowb + r;
                const float csi = csq[row];
                float rowpart = 0.f;
#pragma unroll
                for (int ni = 0; ni < 4; ++ni) {
                    const int col = colb + ni * 16;
                    float sq = csi + csj[ni] - 2.0f * acc[mi][ni][r];
                    float dist = sqrtf(fmaxf(sq, 0.f) + EPSF);
                    float w = fmaxf(0.f, 1.f - dist);
                    float sval = (row == col) ? 0.f : (0.1f * w / (dist + EPSF));
                    S[(long)row * 512 + col] = sval;
                    rowpart += sval;
                }
                atomicAdd(&rs_s[row - m0], rowpart);
            }
        }
        __syncthreads();
        if (tid < 128) atomicAdd(&rsum[m0 + tid], rs_s[tid]);
    }
}

// ---------------- fused WSp-reduce + repulsion-apply + momentum update ----------------
__global__ __launch_bounds__(256) void apply_update(const float* __restrict__ Cent,
                                                    const float* __restrict__ Mom,
                                                    const float* __restrict__ S,
                                                    const float* __restrict__ rsum,
                                                    const float* __restrict__ WSp,
                                                    const float* __restrict__ sum_w,
                                                    float* __restrict__ outC,
                                                    float* __restrict__ outM) {
    const int i = blockIdx.x;
    __shared__ float srow[512];
    __shared__ int nz;
    const int tid = threadIdx.x;
    if (tid == 0) nz = 0;
    __syncthreads();
    float2 sv = *(const float2*)(S + (long)i * 512 + tid * 2);
    srow[tid * 2] = sv.x;
    srow[tid * 2 + 1] = sv.y;
    if (sv.x != 0.f || sv.y != 0.f) nz = 1;
    __syncthreads();
    const float rs = rsum[i];
    const float invw = 1.0f / (sum_w[i] + EPSF);
    const int d0 = tid * 2;
    float ws0 = 0.f, ws1 = 0.f;
#pragma unroll 4
    for (int z = 0; z < 32; ++z) {
        float2 w = *(const float2*)(WSp + (size_t)z * 262144 + (long)i * 512 + d0);
        ws0 += w.x;
        ws1 += w.y;
    }
    float sc0 = 0.f, sc1 = 0.f;
    if (nz) {
        for (int j = 0; j < 512; ++j) {
            const float s = srow[j];
            if (s != 0.f) {
                sc0 += s * Cent[(long)j * 512 + d0];
                sc1 += s * Cent[(long)j * 512 + d0 + 1];
            }
        }
    }
    float2 ci = *(const float2*)(Cent + (long)i * 512 + d0);
    float2 mo = *(const float2*)(Mom + (long)i * 512 + d0);
    float rep0 = rs * ci.x - sc0;
    float rep1 = rs * ci.y - sc1;
    float mn0 = 0.9f * mo.x + 0.1f * (ws0 * invw - ci.x + rep0);
    float mn1 = 0.9f * mo.y + 0.1f * (ws1 * invw - ci.y + rep1);
    float2 om = {mn0, mn1};
    float2 oc = {ci.x + 0.1f * mn0, ci.y + 0.1f * mn1};
    *(float2*)(outM + (long)i * 512 + d0) = om;
    *(float2*)(outC + (long)i * 512 + d0) = oc;
}

// ================= legacy fp32 fallback kernels (small-ws path) =================
__global__ __launch_bounds__(256) void csq_only(const float* __restrict__ C,
                                                float* __restrict__ csq) {
    const int wave = threadIdx.x >> 6, lane = threadIdx.x & 63;
    const int row = blockIdx.x * 4 + wave;
    const float* p = C + row * 512 + lane * 8;
    float4 a = *(const float4*)p;
    float4 b = *(const float4*)(p + 4);
    float s = a.x * a.x + a.y * a.y + a.z * a.z + a.w * a.w +
              b.x * b.x + b.y * b.y + b.z * b.z + b.w * b.w;
#pragma unroll
    for (int off = 1; off < 64; off <<= 1) s += __shfl_xor(s, off, 64);
    if (lane == 0) csq[row] = s;
}

__global__ __launch_bounds__(256) void logits_mfma(const float* __restrict__ X,
                                                   const float* __restrict__ Cm,
                                                   const float* __restrict__ csq,
                                                   float* __restrict__ L) {
    __shared__ ushort sAh[128][64];
    __shared__ ushort sAl[128][64];
    __shared__ ushort sBh[128][64];
    __shared__ ushort sBl[128][64];
    const int tid = threadIdx.x;
    const int m0 = blockIdx.x * 128;
    const int n0 = blockIdx.y * 128;
    const int wid = tid >> 6, lane = tid & 63;
    const int wm = wid >> 1, wn = wid & 1;
    const int lrow = lane & 15;
    const int lkb = lane >> 4;
    f32x4v acc[4][4] = {};
    for (int k0 = 0; k0 < 512; k0 += 64) {
        __syncthreads();
#pragma unroll
        for (int s = 0; s < 8; ++s) {
            const int idx = s * 256 + tid;
            const int r = idx >> 4;
            const int c4 = (idx & 15) << 2;
            const int e = c4 ^ ((r & 7) << 3);
            float4 va = *(const float4*)(X + (long)(m0 + r) * 512 + k0 + c4);
            ushort4 hh, ll;
            split2(va.x, hh.x, ll.x);
            split2(va.y, hh.y, ll.y);
            split2(va.z, hh.z, ll.z);
            split2(va.w, hh.w, ll.w);
            *(ushort4*)&sAh[r][e] = hh;
            *(ushort4*)&sAl[r][e] = ll;
            float4 vb = *(const float4*)(Cm + (long)(n0 + r) * 512 + k0 + c4);
            split2(vb.x, hh.x, ll.x);
            split2(vb.y, hh.y, ll.y);
            split2(vb.z, hh.z, ll.z);
            split2(vb.w, hh.w, ll.w);
            *(ushort4*)&sBh[r][e] = hh;
            *(ushort4*)&sBl[r][e] = ll;
        }
        __syncthreads();
#pragma unroll
        for (int kk = 0; kk < 2; ++kk) {
            const int ebase = kk * 32 + lkb * 8;
            bf16x8 ah[4], al[4], bh[4], bl[4];
#pragma unroll
            for (int mi = 0; mi < 4; ++mi) {
                const int R = wm * 64 + mi * 16 + lrow;
                const int e = ebase ^ ((R & 7) << 3);
                ah[mi] = *(const bf16x8*)&sAh[R][e];
                al[mi] = *(const bf16x8*)&sAl[R][e];
            }
#pragma unroll
            for (int ni = 0; ni < 4; ++ni) {
                const int Rn = wn * 64 + ni * 16 + lrow;
                const int e = ebase ^ ((Rn & 7) << 3);
                bh[ni] = *(const bf16x8*)&sBh[Rn][e];
                bl[ni] = *(const bf16x8*)&sBl[Rn][e];
            }
#pragma unroll
            for (int mi = 0; mi < 4; ++mi)
#pragma unroll
                for (int ni = 0; ni < 4; ++ni) {
                    acc[mi][ni] = __builtin_amdgcn_mfma_f32_16x16x32_bf16(ah[mi], bh[ni], acc[mi][ni], 0, 0, 0);
                    acc[mi][ni] = __builtin_amdgcn_mfma_f32_16x16x32_bf16(ah[mi], bl[ni], acc[mi][ni], 0, 0, 0);
                    acc[mi][ni] = __builtin_amdgcn_mfma_f32_16x16x32_bf16(al[mi], bh[ni], acc[mi][ni], 0, 0, 0);
                }
        }
    }
    const int colb = n0 + wn * 64 + lrow;
    float cs[4];
#pragma unroll
    for (int ni = 0; ni < 4; ++ni) cs[ni] = csq[colb + ni * 16];
#pragma unroll
    for (int mi = 0; mi < 4; ++mi) {
        const int rowb = m0 + wm * 64 + mi * 16 + lkb * 4;
#pragma unroll
        for (int r = 0; r < 4; ++r) {
            float* Lp = L + (long)(rowb + r) * 512 + colb;
#pragma unroll
            for (int ni = 0; ni < 4; ++ni)
                Lp[ni * 16] = 2.0f * acc[mi][ni][r] - cs[ni];
        }
    }
}

__global__ __launch_bounds__(256) void softmax_rows(float* __restrict__ L,
                                                    float* __restrict__ sum_w,
                                                    ushort* __restrict__ Abf) {
    __shared__ float swacc[512];
    const int tid = threadIdx.x;
    for (int i = tid; i < 512; i += 256) swacc[i] = 0.f;
    __syncthreads();
    const int wave = tid >> 6, lane = tid & 63;
    float racc[8] = {};
    for (int r = blockIdx.x * 4 + wave; r < 32768; r += 2048) {
        float* p = L + (long)r * 512 + lane * 8;
        float4 v0 = *(float4*)p;
        float4 v1 = *(float4*)(p + 4);
        float v[8] = {v0.x, v0.y, v0.z, v0.w, v1.x, v1.y, v1.z, v1.w};
        float m = v[0];
#pragma unroll
        for (int i = 1; i < 8; ++i) m = fmaxf(m, v[i]);
#pragma unroll
        for (int off = 1; off < 64; off <<= 1) m = fmaxf(m, __shfl_xor(m, off, 64));
        float e[8], s = 0.f;
#pragma unroll
        for (int i = 0; i < 8; ++i) {
            e[i] = expf((v[i] - m) * 10.0f);
            s += e[i];
        }
#pragma unroll
        for (int off = 1; off < 64; off <<= 1) s += __shfl_xor(s, off, 64);
        const float inv = 1.0f / (s + EPSF);
        ushort eb[8];
#pragma unroll
        for (int i = 0; i < 8; ++i) {
            e[i] *= inv;
            racc[i] += e[i];
            eb[i] = f2bf_bits(e[i]);
        }
        float4 o0 = {e[0], e[1], e[2], e[3]};
        float4 o1 = {e[4], e[5], e[6], e[7]};
        *(float4*)p = o0;
        *(float4*)(p + 4) = o1;
        if (Abf) *(uint4*)(Abf + (long)r * 512 + lane * 8) = pack8(eb);
    }
#pragma unroll
    for (int i = 0; i < 8; ++i) atomicAdd(&swacc[lane * 8 + i], racc[i]);
    __syncthreads();
    for (int i = tid; i < 512; i += 256) atomicAdd(&sum_w[i], swacc[i]);
}

__global__ __launch_bounds__(256) void gemm_wsum(const float* __restrict__ A,
                                                 const float* __restrict__ X,
                                                 float* __restrict__ WS) {
    __shared__ float As[16][64];
    __shared__ float Xs[16][64];
    const int tid = threadIdx.x;
    const int tx = tid & 15, ty = tid >> 4;
    const int lrow = tid >> 4;
    const int lcol = (tid & 15) << 2;
    const int k0 = blockIdx.x * 64;
    const int d0 = blockIdx.y * 64;
    const int n0 = blockIdx.z * 1024;
    float acc[4][4] = {};
    for (int nc = 0; nc < 1024; nc += 16) {
        const long nrow = n0 + nc + lrow;
        float4 av = *(const float4*)(A + nrow * 512 + k0 + lcol);
        float4 xv = *(const float4*)(X + nrow * 512 + d0 + lcol);
        __syncthreads();
        *(float4*)&As[lrow][lcol] = av;
        *(float4*)&Xs[lrow][lcol] = xv;
        __syncthreads();
#pragma unroll
        for (int nn = 0; nn < 16; ++nn) {
            float4 a = *(const float4*)&As[nn][ty << 2];
            float4 x = *(const float4*)&Xs[nn][tx << 2];
            float aa[4] = {a.x, a.y, a.z, a.w};
            float xx[4] = {x.x, x.y, x.z, x.w};
#pragma unroll
            for (int i = 0; i < 4; ++i)
#pragma unroll
                for (int j = 0; j < 4; ++j) acc[i][j] += aa[i] * xx[j];
        }
    }
#pragma unroll
    for (int i = 0; i < 4; ++i)
#pragma unroll
        for (int j = 0; j < 4; ++j)
            atomicAdd(&WS[(k0 + (ty << 2) + i) * 512 + d0 + (tx << 2) + j], acc[i][j]);
}

__global__ __launch_bounds__(256) void repulse_update(const float* __restrict__ Cent,
                                                      const float* __restrict__ Mom,
                                                      const float* __restrict__ csq,
                                                      const float* __restrict__ WS,
                                                      const float* __restrict__ sum_w,
                                                      float* __restrict__ outC,
                                                      float* __restrict__ outM) {
    const int i = blockIdx.x;
    __shared__ float ci[512];
    __shared__ float rep[512];
    const int tid = threadIdx.x, wave = tid >> 6, lane = tid & 63;
    for (int d = tid; d < 512; d += 256) {
        ci[d] = Cent[i * 512 + d];
        rep[d] = 0.f;
    }
    __syncthreads();
    float cil[8];
#pragma unroll
    for (int m = 0; m < 8; ++m) cil[m] = ci[lane * 8 + m];
    const float csqi = csq[i];
    float racc[8] = {};
    for (int j = wave; j < 512; j += 4) {
        if (j == i) continue;
        const float* cj = Cent + j * 512 + lane * 8;
        float4 c0 = *(const float4*)cj;
        float4 c1 = *(const float4*)(cj + 4);
        float cjl[8] = {c0.x, c0.y, c0.z, c0.w, c1.x, c1.y, c1.z, c1.w};
        float dot = 0.f;
#pragma unroll
        for (int m = 0; m < 8; ++m) dot += cil[m] * cjl[m];
#pragma unroll
        for (int off = 1; off < 64; off <<= 1) dot += __shfl_xor(dot, off, 64);
        float sq = csqi + csq[j] - 2.f * dot;
        float dist = sqrtf(fmaxf(sq, 0.f) + EPSF);
        float w = fmaxf(0.f, 1.f - dist);
        float scale = 0.1f * w / (dist + EPSF);
#pragma unroll
        for (int m = 0; m < 8; ++m) racc[m] += scale * (cil[m] - cjl[m]);
    }
#pragma unroll
    for (int m = 0; m < 8; ++m) atomicAdd(&rep[lane * 8 + m], racc[m]);
    __syncthreads();
    const float invw = 1.0f / (sum_w[i] + EPSF);
    for (int d = tid; d < 512; d += 256) {
        float nc = WS[i * 512 + d] * invw;
        float upd = nc - ci[d] + rep[d];
        float mn = 0.9f * Mom[i * 512 + d] + 0.1f * upd;
        outM[i * 512 + d] = mn;
        outC[i * 512 + d] = ci[d] + 0.1f * mn;
    }
}

extern "C" void kernel_launch(void* const* d_in, const int* in_sizes, int n_in,
                              void* d_out, int out_size, void* d_ws, size_t ws_size,
                              hipStream_t stream) {
    const float* X = (const float*)d_in[0];      // (32768, 512)
    const float* C = (const float*)d_in[1];      // (512, 512)
    const float* M = (const float*)d_in[2];      // (512, 512)
    float* out = (float*)d_out;
    float* assign = out;                          // 32768*512
    float* outC = out + 16777216;                 // 512*512
    float* outM = outC + 262144;                  // 512*512

    char* wsb = (char*)d_ws;
    const size_t MB = 1024ull * 1024ull;
    float* WS = (float*)wsb;                            // 1 MB (fallback only)
    float* sum_w = (float*)(wsb + 1 * MB);              // 2 KB
    float* rsum = (float*)(wsb + 1 * MB + 2048);        // 2 KB
    float* csq = (float*)(wsb + 1 * MB + 4096);         // 2 KB
    ushort* Chl = (ushort*)(wsb + 2 * MB);              // 1 MB (512 x 1024 bf16)
    float* S = (float*)(wsb + 3 * MB);                  // 1 MB
    float* WSp = (float*)(wsb + 4 * MB);                // 32 MB (z=32)
    ushort* Xh = (ushort*)(wsb + 36 * MB);              // 32 MB (bf16 hi of X)
    ushort* Abf = (ushort*)(wsb + 100 * MB);            // 32 MB
    const size_t NEED = 132 * MB;                       // proven available

    if (ws_size >= NEED) {
        csqc_v3<<<128, 256, 0, stream>>>(C, csq, Chl, sum_w, rsum);
        logsm<<<512, 512, 0, stream>>>(X, Chl, csq, assign, Abf, Xh, sum_w);
        wsum_gram<<<528, 256, 0, stream>>>(Abf, Xh, WSp, Chl, csq, S, rsum);
        apply_update<<<512, 256, 0, stream>>>(C, M, S, rsum, WSp, sum_w, outC, outM);
    } else {
        hipMemsetAsync(d_ws, 0, 1 * MB + 8192, stream);
        csq_only<<<128, 256, 0, stream>>>(C, csq);
        logits_mfma<<<dim3(256, 4), 256, 0, stream>>>(X, C, csq, assign);
        softmax_rows<<<512, 256, 0, stream>>>(assign, sum_w, nullptr);
        gemm_wsum<<<dim3(8, 8, 32), 256, 0, stream>>>(assign, X, WS);
        repulse_update<<<512, 256, 0, stream>>>(C, M, csq, WS, sum_w, outC, outM);
    }
}

// Round 15
// 142.951 us; speedup vs baseline: 1.1969x; 1.1969x over previous
//
#include <hip/hip_runtime.h>
#include <hip/hip_bf16.h>

#define EPSF 1e-7f

typedef __attribute__((ext_vector_type(8))) short bf16x8;
typedef __attribute__((ext_vector_type(4))) float f32x4v;

__device__ inline ushort f2bf_bits(float x) {
    union { __hip_bfloat16 b; ushort u; } cv;
    cv.b = __float2bfloat16(x);
    return cv.u;
}
__device__ inline float bfbits2f(ushort u) {
    union { ushort u; __hip_bfloat16 b; } cv;
    cv.u = u;
    return __bfloat162float(cv.b);
}
__device__ inline void split2(float x, ushort& h, ushort& l) {
    h = f2bf_bits(x);
    l = f2bf_bits(x - bfbits2f(h));
}
__device__ inline uint4 pack8(const ushort* h) {
    uint4 p;
    p.x = (uint)h[0] | ((uint)h[1] << 16);
    p.y = (uint)h[2] | ((uint)h[3] << 16);
    p.z = (uint)h[4] | ((uint)h[5] << 16);
    p.w = (uint)h[6] | ((uint)h[7] << 16);
    return p;
}

__device__ inline void gload_lds16(const ushort* g, ushort* l) {
    __builtin_amdgcn_global_load_lds(
        (const __attribute__((address_space(1))) unsigned int*)g,
        (__attribute__((address_space(3))) unsigned int*)l, 16, 0, 0);
}

// ---------------- csq + C -> Chl + zero sum_w/rsum (memset folded) ----------------
__global__ __launch_bounds__(256) void csqc_v3(const float* __restrict__ C,
                                               float* __restrict__ csq,
                                               ushort* __restrict__ Chl,
                                               float* __restrict__ sum_w,
                                               float* __restrict__ rsum) {
    const int wave = threadIdx.x >> 6, lane = threadIdx.x & 63;
    const int row = blockIdx.x * 4 + wave;
    const int kc = lane >> 2, s = lane & 3;
    if (blockIdx.x == 0) {
        sum_w[threadIdx.x] = 0.f;
        sum_w[256 + threadIdx.x] = 0.f;
        rsum[threadIdx.x] = 0.f;
        rsum[256 + threadIdx.x] = 0.f;
    }
    const float* p = C + row * 512 + lane * 8;
    float4 a = *(const float4*)p;
    float4 b = *(const float4*)(p + 4);
    float v[8] = {a.x, a.y, a.z, a.w, b.x, b.y, b.z, b.w};
    ushort h[8], l[8];
    float sqs = 0.f;
#pragma unroll
    for (int i = 0; i < 8; ++i) {
        sqs += v[i] * v[i];
        split2(v[i], h[i], l[i]);
    }
    ushort* base = Chl + (long)row * 1024 + kc * 64 + s * 8;
    *(uint4*)base = pack8(h);
    *(uint4*)(base + 32) = pack8(l);
#pragma unroll
    for (int off = 1; off < 64; off <<= 1) sqs += __shfl_xor(sqs, off, 64);
    if (lane == 0) csq[row] = sqs;
}

// ---------------- logsm (R13/R11 version): fused X-convert + logits GEMM + row softmax ----------------
// NOTE: this kernel sits exactly at the 64-VGPR occupancy cliff — any extra live
// register (prefetch, setprio restructuring) halves waves/SIMD and costs ~20%.
__global__ __launch_bounds__(512) void logsm(const float* __restrict__ X,
                                             const ushort* __restrict__ Chl,
                                             const float* __restrict__ csq,
                                             float* __restrict__ assign,
                                             ushort* __restrict__ Abf,
                                             ushort* __restrict__ Xh,
                                             float* __restrict__ sum_w) {
    __shared__ __align__(16) ushort sA[64 * 64];      // 8 KB (hi|lo per kc)
    __shared__ __align__(16) ushort sB[512 * 64];     // 64 KB
    __shared__ float rmaxs[64][4];
    __shared__ float rsums[64][4];
    __shared__ float swacc[512];
    const int tid = threadIdx.x;
    const int m0 = ((blockIdx.x & 7) * 64 + (blockIdx.x >> 3)) * 64;
    const int wid = tid >> 6, lane = tid & 63;
    const int wm = wid >> 2, wn = wid & 3;
    const int lrow = lane & 15, lkb = lane >> 4;
    swacc[tid] = 0.f;
    f32x4v acc[2][8] = {};

    const int ar = tid >> 3, aq = tid & 7;   // A-stage task: row 0..63, quad 0..7

#pragma unroll 1
    for (int kc = 0; kc < 16; ++kc) {
        __syncthreads();
        {   // A: load fp32 quad, split to hi/lo, ds_write swizzled; write Xh byproduct
            float4 v = *(const float4*)(X + (long)(m0 + ar) * 512 + kc * 32 + aq * 4);
            ushort h[4], l[4];
            split2(v.x, h[0], l[0]);
            split2(v.y, h[1], l[1]);
            split2(v.z, h[2], l[2]);
            split2(v.w, h[3], l[3]);
            ushort4 hv = {h[0], h[1], h[2], h[3]};
            ushort4 lv = {l[0], l[1], l[2], l[3]};
            const int sh = (aq >> 1) ^ (ar & 7);
            const int slo = ((aq >> 1) + 4) ^ (ar & 7);
            *(ushort4*)&sA[ar * 64 + (sh << 3) + (aq & 1) * 4] = hv;
            *(ushort4*)&sA[ar * 64 + (slo << 3) + (aq & 1) * 4] = lv;
            *(ushort4*)(Xh + (long)(m0 + ar) * 512 + kc * 32 + aq * 4) = hv;
        }
#pragma unroll
        for (int i = 0; i < 8; ++i) {   // B: 512 rows = 4096 slots, 8/thread
            const int sl = i * 512 + tid;
            const int r = sl >> 3, j = sl & 7;
            const int s = j ^ (r & 7);
            gload_lds16(Chl + (long)r * 1024 + kc * 64 + s * 8,
                        &sB[(i * 512 + wid * 64) * 8]);
        }
        __syncthreads();
        bf16x8 ah[2], al[2];
#pragma unroll
        for (int mi = 0; mi < 2; ++mi) {
            const int R = wm * 32 + mi * 16 + lrow;
            ah[mi] = *(const bf16x8*)&sA[R * 64 + ((lkb ^ (R & 7)) << 3)];
            al[mi] = *(const bf16x8*)&sA[R * 64 + (((lkb + 4) ^ (R & 7)) << 3)];
        }
#pragma unroll
        for (int ni = 0; ni < 8; ++ni) {
            const int Rn = wn * 128 + ni * 16 + lrow;
            bf16x8 bh = *(const bf16x8*)&sB[Rn * 64 + ((lkb ^ (Rn & 7)) << 3)];
            bf16x8 bl = *(const bf16x8*)&sB[Rn * 64 + (((lkb + 4) ^ (Rn & 7)) << 3)];
#pragma unroll
            for (int mi = 0; mi < 2; ++mi) {
                acc[mi][ni] = __builtin_amdgcn_mfma_f32_16x16x32_bf16(ah[mi], bh, acc[mi][ni], 0, 0, 0);
                acc[mi][ni] = __builtin_amdgcn_mfma_f32_16x16x32_bf16(ah[mi], bl, acc[mi][ni], 0, 0, 0);
                acc[mi][ni] = __builtin_amdgcn_mfma_f32_16x16x32_bf16(al[mi], bh, acc[mi][ni], 0, 0, 0);
            }
        }
    }
    // ---- epilogue: logits -> softmax -> outputs ----
    const int colb = wn * 128 + lrow;
    float cs[8];
#pragma unroll
    for (int ni = 0; ni < 8; ++ni) cs[ni] = csq[colb + ni * 16];
    float mx[2][4];
#pragma unroll
    for (int mi = 0; mi < 2; ++mi)
#pragma unroll
        for (int r = 0; r < 4; ++r) {
            float m = -3.0e38f;
#pragma unroll
            for (int ni = 0; ni < 8; ++ni) {
                float l = 2.0f * acc[mi][ni][r] - cs[ni];
                acc[mi][ni][r] = l;
                m = fmaxf(m, l);
            }
            mx[mi][r] = m;
        }
#pragma unroll
    for (int off = 1; off < 16; off <<= 1)
#pragma unroll
        for (int mi = 0; mi < 2; ++mi)
#pragma unroll
            for (int r = 0; r < 4; ++r) mx[mi][r] = fmaxf(mx[mi][r], __shfl_xor(mx[mi][r], off, 64));
    if (lrow == 0) {
#pragma unroll
        for (int mi = 0; mi < 2; ++mi)
#pragma unroll
            for (int r = 0; r < 4; ++r) rmaxs[wm * 32 + mi * 16 + lkb * 4 + r][wn] = mx[mi][r];
    }
    __syncthreads();
    float gmax[2][4];
#pragma unroll
    for (int mi = 0; mi < 2; ++mi)
#pragma unroll
        for (int r = 0; r < 4; ++r) {
            const int row = wm * 32 + mi * 16 + lkb * 4 + r;
            gmax[mi][r] = fmaxf(fmaxf(rmaxs[row][0], rmaxs[row][1]),
                                fmaxf(rmaxs[row][2], rmaxs[row][3]));
        }
    float sm[2][4] = {};
#pragma unroll
    for (int mi = 0; mi < 2; ++mi)
#pragma unroll
        for (int ni = 0; ni < 8; ++ni)
#pragma unroll
            for (int r = 0; r < 4; ++r) {
                float e = expf((acc[mi][ni][r] - gmax[mi][r]) * 10.0f);
                acc[mi][ni][r] = e;
                sm[mi][r] += e;
            }
#pragma unroll
    for (int off = 1; off < 16; off <<= 1)
#pragma unroll
        for (int mi = 0; mi < 2; ++mi)
#pragma unroll
            for (int r = 0; r < 4; ++r) sm[mi][r] += __shfl_xor(sm[mi][r], off, 64);
    if (lrow == 0) {
#pragma unroll
        for (int mi = 0; mi < 2; ++mi)
#pragma unroll
            for (int r = 0; r < 4; ++r) rsums[wm * 32 + mi * 16 + lkb * 4 + r][wn] = sm[mi][r];
    }
    __syncthreads();
    float inv[2][4];
#pragma unroll
    for (int mi = 0; mi < 2; ++mi)
#pragma unroll
        for (int r = 0; r < 4; ++r) {
            const int row = wm * 32 + mi * 16 + lkb * 4 + r;
            float t = rsums[row][0] + rsums[row][1] + rsums[row][2] + rsums[row][3];
            inv[mi][r] = 1.0f / (t + EPSF);
        }
    float csum[8] = {};
#pragma unroll
    for (int mi = 0; mi < 2; ++mi)
#pragma unroll
        for (int ni = 0; ni < 8; ++ni) {
            const int col = colb + ni * 16;
#pragma unroll
            for (int r = 0; r < 4; ++r) {
                const int row = wm * 32 + mi * 16 + lkb * 4 + r;
                float a = acc[mi][ni][r] * inv[mi][r];
                assign[(long)(m0 + row) * 512 + col] = a;
                Abf[(long)(m0 + row) * 512 + col] = f2bf_bits(a);
                csum[ni] += a;
            }
        }
#pragma unroll
    for (int off = 16; off < 64; off <<= 1)
#pragma unroll
        for (int ni = 0; ni < 8; ++ni) csum[ni] += __shfl_xor(csum[ni], off, 64);
    if (lkb == 0) {
#pragma unroll
        for (int ni = 0; ni < 8; ++ni) atomicAdd(&swacc[colb + ni * 16], csum[ni]);
    }
    __syncthreads();
    atomicAdd(&sum_w[tid], swacc[tid]);
}

// ---------------- wsum (dbuf) + gram merged: blocks 0..511 wsum, 512..527 gram ----------------
__global__ __launch_bounds__(256) void wsum_gram(const ushort* __restrict__ Abf,
                                                 const ushort* __restrict__ Xh,
                                                 float* __restrict__ WSp,
                                                 const ushort* __restrict__ Chl,
                                                 const float* __restrict__ csq,
                                                 float* __restrict__ S,
                                                 float* __restrict__ rsum) {
    __shared__ __align__(16) ushort sA[2][128 * 64];   // 2 x 16 KB
    __shared__ __align__(16) ushort sB[2][128 * 64];
    __shared__ float rs_s[128];
    const int tid = threadIdx.x;
    const int bid = blockIdx.x;
    const int wid = tid >> 6, lane = tid & 63;
    const int wm = wid >> 1, wn = wid & 1;
    const int lrow = lane & 15, lkb = lane >> 4;
    f32x4v acc[4][4] = {};

    if (bid < 512) {
        const int T = (bid & 7) * 64 + (bid >> 3);
        const int k0 = (T & 3) * 128;
        const int d0 = ((T >> 2) & 3) * 128;
        const int zc = T >> 4;                 // 0..31
        const long n0 = (long)zc * 1024;
        ushort ha[4][8], hx[4][8];

#define WSUM_LOAD(NCOFF)                                                      \
        {                                                                      \
            _Pragma("unroll")                                                  \
            for (int it = 0; it < 4; ++it) {                                   \
                const int idx = it * 256 + tid;                                \
                const int c = idx & 127;                                       \
                const int no = idx >> 7;                                       \
                const long nb = n0 + (NCOFF) + (long)no * 8;                   \
                _Pragma("unroll")                                              \
                for (int jj = 0; jj < 8; ++jj) {                               \
                    ha[it][jj] = Abf[(nb + jj) * 512 + k0 + c];                \
                    hx[it][jj] = Xh[(nb + jj) * 512 + d0 + c];                 \
                }                                                              \
            }                                                                  \
        }
#define WSUM_WRITE(B)                                                         \
        {                                                                      \
            _Pragma("unroll")                                                  \
            for (int it = 0; it < 4; ++it) {                                   \
                const int idx = it * 256 + tid;                                \
                const int c = idx & 127;                                       \
                const int no = idx >> 7;                                       \
                const int sl = no ^ (c & 7);                                   \
                *(uint4*)&sA[(B)][c * 64 + sl * 8] = pack8(ha[it]);            \
                *(uint4*)&sB[(B)][c * 64 + sl * 8] = pack8(hx[it]);            \
            }                                                                  \
        }

        WSUM_LOAD(0);
        WSUM_WRITE(0);
        int cur = 0;
#pragma unroll 1
        for (int nc = 0; nc < 16; ++nc) {
            if (nc < 15) WSUM_LOAD((nc + 1) * 64);
            __syncthreads();
#pragma unroll
            for (int kk = 0; kk < 2; ++kk) {
                const int j = kk * 4 + lkb;
                bf16x8 af[4], bfv[4];
#pragma unroll
                for (int mi = 0; mi < 4; ++mi) {
                    const int R = wm * 64 + mi * 16 + lrow;
                    af[mi] = *(const bf16x8*)&sA[cur][R * 64 + ((j ^ (R & 7)) << 3)];
                }
#pragma unroll
                for (int ni = 0; ni < 4; ++ni) {
                    const int R = wn * 64 + ni * 16 + lrow;
                    bfv[ni] = *(const bf16x8*)&sB[cur][R * 64 + ((j ^ (R & 7)) << 3)];
                }
#pragma unroll
                for (int mi = 0; mi < 4; ++mi)
#pragma unroll
                    for (int ni = 0; ni < 4; ++ni)
                        acc[mi][ni] = __builtin_amdgcn_mfma_f32_16x16x32_bf16(af[mi], bfv[ni], acc[mi][ni], 0, 0, 0);
            }
            if (nc < 15) WSUM_WRITE(cur ^ 1);
            cur ^= 1;
        }
        float* dst = WSp + (size_t)zc * 262144;
#pragma unroll
        for (int mi = 0; mi < 4; ++mi) {
            const int k = k0 + wm * 64 + mi * 16 + lkb * 4;
#pragma unroll
            for (int ni = 0; ni < 4; ++ni) {
                const int d = d0 + wn * 64 + ni * 16 + lrow;
#pragma unroll
                for (int r = 0; r < 4; ++r)
                    dst[(k + r) * 512 + d] = acc[mi][ni][r];
            }
        }
#undef WSUM_LOAD
#undef WSUM_WRITE
    } else {
        const int g = bid - 512;               // 0..15
        const int n0 = (g & 3) * 128;
        const int m0 = (g >> 2) * 128;
#pragma unroll 1
        for (int kc = 0; kc < 16; ++kc) {
            __syncthreads();
#pragma unroll
            for (int i = 0; i < 4; ++i) {
                const int sl = wid * 256 + i * 64 + lane;
                const int r = sl >> 3, j = sl & 7;
                const int s = j ^ (r & 7);
                gload_lds16(Chl + (long)(m0 + r) * 1024 + kc * 64 + s * 8,
                            &sA[0][(wid * 256 + i * 64) * 8]);
                gload_lds16(Chl + (long)(n0 + r) * 1024 + kc * 64 + s * 8,
                            &sB[0][(wid * 256 + i * 64) * 8]);
            }
            __syncthreads();
            bf16x8 ah[4], al[4], bh[4], bl[4];
#pragma unroll
            for (int mi = 0; mi < 4; ++mi) {
                const int R = wm * 64 + mi * 16 + lrow;
                ah[mi] = *(const bf16x8*)&sA[0][R * 64 + ((lkb ^ (R & 7)) << 3)];
                al[mi] = *(const bf16x8*)&sA[0][R * 64 + (((lkb + 4) ^ (R & 7)) << 3)];
            }
#pragma unroll
            for (int ni = 0; ni < 4; ++ni) {
                const int R = wn * 64 + ni * 16 + lrow;
                bh[ni] = *(const bf16x8*)&sB[0][R * 64 + ((lkb ^ (R & 7)) << 3)];
                bl[ni] = *(const bf16x8*)&sB[0][R * 64 + (((lkb + 4) ^ (R & 7)) << 3)];
            }
#pragma unroll
            for (int mi = 0; mi < 4; ++mi)
#pragma unroll
                for (int ni = 0; ni < 4; ++ni) {
                    acc[mi][ni] = __builtin_amdgcn_mfma_f32_16x16x32_bf16(ah[mi], bh[ni], acc[mi][ni], 0, 0, 0);
                    acc[mi][ni] = __builtin_amdgcn_mfma_f32_16x16x32_bf16(ah[mi], bl[ni], acc[mi][ni], 0, 0, 0);
                    acc[mi][ni] = __builtin_amdgcn_mfma_f32_16x16x32_bf16(al[mi], bh[ni], acc[mi][ni], 0, 0, 0);
                }
        }
        if (tid < 128) rs_s[tid] = 0.f;
        __syncthreads();
        const int colb = n0 + wn * 64 + lrow;
        float csj[4];
#pragma unroll
        for (int ni = 0; ni < 4; ++ni) csj[ni] = csq[colb + ni * 16];
#pragma unroll
        for (int mi = 0; mi < 4; ++mi) {
            const int rowb = m0 + wm * 64 + mi * 16 + lkb * 4;
#pragma unroll
            for (int r = 0; r < 4; ++r) {
                const int row = rowb + r;
                const float csi = csq[row];
                float rowpart = 0.f;
#pragma unroll
                for (int ni = 0; ni < 4; ++ni) {
                    const int col = colb + ni * 16;
                    float sq = csi + csj[ni] - 2.0f * acc[mi][ni][r];
                    float dist = sqrtf(fmaxf(sq, 0.f) + EPSF);
                    float w = fmaxf(0.f, 1.f - dist);
                    float sval = (row == col) ? 0.f : (0.1f * w / (dist + EPSF));
                    S[(long)row * 512 + col] = sval;
                    rowpart += sval;
                }
                atomicAdd(&rs_s[row - m0], rowpart);
            }
        }
        __syncthreads();
        if (tid < 128) atomicAdd(&rsum[m0 + tid], rs_s[tid]);
    }
}

// ---------------- fused WSp-reduce + repulsion-apply + momentum update ----------------
__global__ __launch_bounds__(256) void apply_update(const float* __restrict__ Cent,
                                                    const float* __restrict__ Mom,
                                                    const float* __restrict__ S,
                                                    const float* __restrict__ rsum,
                                                    const float* __restrict__ WSp,
                                                    const float* __restrict__ sum_w,
                                                    float* __restrict__ outC,
                                                    float* __restrict__ outM) {
    const int i = blockIdx.x;
    __shared__ float srow[512];
    __shared__ int nz;
    const int tid = threadIdx.x;
    if (tid == 0) nz = 0;
    __syncthreads();
    float2 sv = *(const float2*)(S + (long)i * 512 + tid * 2);
    srow[tid * 2] = sv.x;
    srow[tid * 2 + 1] = sv.y;
    if (sv.x != 0.f || sv.y != 0.f) nz = 1;
    __syncthreads();
    const float rs = rsum[i];
    const float invw = 1.0f / (sum_w[i] + EPSF);
    const int d0 = tid * 2;
    float ws0 = 0.f, ws1 = 0.f;
#pragma unroll 4
    for (int z = 0; z < 32; ++z) {
        float2 w = *(const float2*)(WSp + (size_t)z * 262144 + (long)i * 512 + d0);
        ws0 += w.x;
        ws1 += w.y;
    }
    float sc0 = 0.f, sc1 = 0.f;
    if (nz) {
        for (int j = 0; j < 512; ++j) {
            const float s = srow[j];
            if (s != 0.f) {
                sc0 += s * Cent[(long)j * 512 + d0];
                sc1 += s * Cent[(long)j * 512 + d0 + 1];
            }
        }
    }
    float2 ci = *(const float2*)(Cent + (long)i * 512 + d0);
    float2 mo = *(const float2*)(Mom + (long)i * 512 + d0);
    float rep0 = rs * ci.x - sc0;
    float rep1 = rs * ci.y - sc1;
    float mn0 = 0.9f * mo.x + 0.1f * (ws0 * invw - ci.x + rep0);
    float mn1 = 0.9f * mo.y + 0.1f * (ws1 * invw - ci.y + rep1);
    float2 om = {mn0, mn1};
    float2 oc = {ci.x + 0.1f * mn0, ci.y + 0.1f * mn1};
    *(float2*)(outM + (long)i * 512 + d0) = om;
    *(float2*)(outC + (long)i * 512 + d0) = oc;
}

// ================= legacy fp32 fallback kernels (small-ws path) =================
__global__ __launch_bounds__(256) void csq_only(const float* __restrict__ C,
                                                float* __restrict__ csq) {
    const int wave = threadIdx.x >> 6, lane = threadIdx.x & 63;
    const int row = blockIdx.x * 4 + wave;
    const float* p = C + row * 512 + lane * 8;
    float4 a = *(const float4*)p;
    float4 b = *(const float4*)(p + 4);
    float s = a.x * a.x + a.y * a.y + a.z * a.z + a.w * a.w +
              b.x * b.x + b.y * b.y + b.z * b.z + b.w * b.w;
#pragma unroll
    for (int off = 1; off < 64; off <<= 1) s += __shfl_xor(s, off, 64);
    if (lane == 0) csq[row] = s;
}

__global__ __launch_bounds__(256) void logits_mfma(const float* __restrict__ X,
                                                   const float* __restrict__ Cm,
                                                   const float* __restrict__ csq,
                                                   float* __restrict__ L) {
    __shared__ ushort sAh[128][64];
    __shared__ ushort sAl[128][64];
    __shared__ ushort sBh[128][64];
    __shared__ ushort sBl[128][64];
    const int tid = threadIdx.x;
    const int m0 = blockIdx.x * 128;
    const int n0 = blockIdx.y * 128;
    const int wid = tid >> 6, lane = tid & 63;
    const int wm = wid >> 1, wn = wid & 1;
    const int lrow = lane & 15;
    const int lkb = lane >> 4;
    f32x4v acc[4][4] = {};
    for (int k0 = 0; k0 < 512; k0 += 64) {
        __syncthreads();
#pragma unroll
        for (int s = 0; s < 8; ++s) {
            const int idx = s * 256 + tid;
            const int r = idx >> 4;
            const int c4 = (idx & 15) << 2;
            const int e = c4 ^ ((r & 7) << 3);
            float4 va = *(const float4*)(X + (long)(m0 + r) * 512 + k0 + c4);
            ushort4 hh, ll;
            split2(va.x, hh.x, ll.x);
            split2(va.y, hh.y, ll.y);
            split2(va.z, hh.z, ll.z);
            split2(va.w, hh.w, ll.w);
            *(ushort4*)&sAh[r][e] = hh;
            *(ushort4*)&sAl[r][e] = ll;
            float4 vb = *(const float4*)(Cm + (long)(n0 + r) * 512 + k0 + c4);
            split2(vb.x, hh.x, ll.x);
            split2(vb.y, hh.y, ll.y);
            split2(vb.z, hh.z, ll.z);
            split2(vb.w, hh.w, ll.w);
            *(ushort4*)&sBh[r][e] = hh;
            *(ushort4*)&sBl[r][e] = ll;
        }
        __syncthreads();
#pragma unroll
        for (int kk = 0; kk < 2; ++kk) {
            const int ebase = kk * 32 + lkb * 8;
            bf16x8 ah[4], al[4], bh[4], bl[4];
#pragma unroll
            for (int mi = 0; mi < 4; ++mi) {
                const int R = wm * 64 + mi * 16 + lrow;
                const int e = ebase ^ ((R & 7) << 3);
                ah[mi] = *(const bf16x8*)&sAh[R][e];
                al[mi] = *(const bf16x8*)&sAl[R][e];
            }
#pragma unroll
            for (int ni = 0; ni < 4; ++ni) {
                const int Rn = wn * 64 + ni * 16 + lrow;
                const int e = ebase ^ ((Rn & 7) << 3);
                bh[ni] = *(const bf16x8*)&sBh[Rn][e];
                bl[ni] = *(const bf16x8*)&sBl[Rn][e];
            }
#pragma unroll
            for (int mi = 0; mi < 4; ++mi)
#pragma unroll
                for (int ni = 0; ni < 4; ++ni) {
                    acc[mi][ni] = __builtin_amdgcn_mfma_f32_16x16x32_bf16(ah[mi], bh[ni], acc[mi][ni], 0, 0, 0);
                    acc[mi][ni] = __builtin_amdgcn_mfma_f32_16x16x32_bf16(ah[mi], bl[ni], acc[mi][ni], 0, 0, 0);
                    acc[mi][ni] = __builtin_amdgcn_mfma_f32_16x16x32_bf16(al[mi], bh[ni], acc[mi][ni], 0, 0, 0);
                }
        }
    }
    const int colb = n0 + wn * 64 + lrow;
    float cs[4];
#pragma unroll
    for (int ni = 0; ni < 4; ++ni) cs[ni] = csq[colb + ni * 16];
#pragma unroll
    for (int mi = 0; mi < 4; ++mi) {
        const int rowb = m0 + wm * 64 + mi * 16 + lkb * 4;
#pragma unroll
        for (int r = 0; r < 4; ++r) {
            float* Lp = L + (long)(rowb + r) * 512 + colb;
#pragma unroll
            for (int ni = 0; ni < 4; ++ni)
                Lp[ni * 16] = 2.0f * acc[mi][ni][r] - cs[ni];
        }
    }
}

__global__ __launch_bounds__(256) void softmax_rows(float* __restrict__ L,
                                                    float* __restrict__ sum_w,
                                                    ushort* __restrict__ Abf) {
    __shared__ float swacc[512];
    const int tid = threadIdx.x;
    for (int i = tid; i < 512; i += 256) swacc[i] = 0.f;
    __syncthreads();
    const int wave = tid >> 6, lane = tid & 63;
    float racc[8] = {};
    for (int r = blockIdx.x * 4 + wave; r < 32768; r += 2048) {
        float* p = L + (long)r * 512 + lane * 8;
        float4 v0 = *(float4*)p;
        float4 v1 = *(float4*)(p + 4);
        float v[8] = {v0.x, v0.y, v0.z, v0.w, v1.x, v1.y, v1.z, v1.w};
        float m = v[0];
#pragma unroll
        for (int i = 1; i < 8; ++i) m = fmaxf(m, v[i]);
#pragma unroll
        for (int off = 1; off < 64; off <<= 1) m = fmaxf(m, __shfl_xor(m, off, 64));
        float e[8], s = 0.f;
#pragma unroll
        for (int i = 0; i < 8; ++i) {
            e[i] = expf((v[i] - m) * 10.0f);
            s += e[i];
        }
#pragma unroll
        for (int off = 1; off < 64; off <<= 1) s += __shfl_xor(s, off, 64);
        const float inv = 1.0f / (s + EPSF);
        ushort eb[8];
#pragma unroll
        for (int i = 0; i < 8; ++i) {
            e[i] *= inv;
            racc[i] += e[i];
            eb[i] = f2bf_bits(e[i]);
        }
        float4 o0 = {e[0], e[1], e[2], e[3]};
        float4 o1 = {e[4], e[5], e[6], e[7]};
        *(float4*)p = o0;
        *(float4*)(p + 4) = o1;
        if (Abf) *(uint4*)(Abf + (long)r * 512 + lane * 8) = pack8(eb);
    }
#pragma unroll
    for (int i = 0; i < 8; ++i) atomicAdd(&swacc[lane * 8 + i], racc[i]);
    __syncthreads();
    for (int i = tid; i < 512; i += 256) atomicAdd(&sum_w[i], swacc[i]);
}

__global__ __launch_bounds__(256) void gemm_wsum(const float* __restrict__ A,
                                                 const float* __restrict__ X,
                                                 float* __restrict__ WS) {
    __shared__ float As[16][64];
    __shared__ float Xs[16][64];
    const int tid = threadIdx.x;
    const int tx = tid & 15, ty = tid >> 4;
    const int lrow = tid >> 4;
    const int lcol = (tid & 15) << 2;
    const int k0 = blockIdx.x * 64;
    const int d0 = blockIdx.y * 64;
    const int n0 = blockIdx.z * 1024;
    float acc[4][4] = {};
    for (int nc = 0; nc < 1024; nc += 16) {
        const long nrow = n0 + nc + lrow;
        float4 av = *(const float4*)(A + nrow * 512 + k0 + lcol);
        float4 xv = *(const float4*)(X + nrow * 512 + d0 + lcol);
        __syncthreads();
        *(float4*)&As[lrow][lcol] = av;
        *(float4*)&Xs[lrow][lcol] = xv;
        __syncthreads();
#pragma unroll
        for (int nn = 0; nn < 16; ++nn) {
            float4 a = *(const float4*)&As[nn][ty << 2];
            float4 x = *(const float4*)&Xs[nn][tx << 2];
            float aa[4] = {a.x, a.y, a.z, a.w};
            float xx[4] = {x.x, x.y, x.z, x.w};
#pragma unroll
            for (int i = 0; i < 4; ++i)
#pragma unroll
                for (int j = 0; j < 4; ++j) acc[i][j] += aa[i] * xx[j];
        }
    }
#pragma unroll
    for (int i = 0; i < 4; ++i)
#pragma unroll
        for (int j = 0; j < 4; ++j)
            atomicAdd(&WS[(k0 + (ty << 2) + i) * 512 + d0 + (tx << 2) + j], acc[i][j]);
}

__global__ __launch_bounds__(256) void repulse_update(const float* __restrict__ Cent,
                                                      const float* __restrict__ Mom,
                                                      const float* __restrict__ csq,
                                                      const float* __restrict__ WS,
                                                      const float* __restrict__ sum_w,
                                                      float* __restrict__ outC,
                                                      float* __restrict__ outM) {
    const int i = blockIdx.x;
    __shared__ float ci[512];
    __shared__ float rep[512];
    const int tid = threadIdx.x, wave = tid >> 6, lane = tid & 63;
    for (int d = tid; d < 512; d += 256) {
        ci[d] = Cent[i * 512 + d];
        rep[d] = 0.f;
    }
    __syncthreads();
    float cil[8];
#pragma unroll
    for (int m = 0; m < 8; ++m) cil[m] = ci[lane * 8 + m];
    const float csqi = csq[i];
    float racc[8] = {};
    for (int j = wave; j < 512; j += 4) {
        if (j == i) continue;
        const float* cj = Cent + j * 512 + lane * 8;
        float4 c0 = *(const float4*)cj;
        float4 c1 = *(const float4*)(cj + 4);
        float cjl[8] = {c0.x, c0.y, c0.z, c0.w, c1.x, c1.y, c1.z, c1.w};
        float dot = 0.f;
#pragma unroll
        for (int m = 0; m < 8; ++m) dot += cil[m] * cjl[m];
#pragma unroll
        for (int off = 1; off < 64; off <<= 1) dot += __shfl_xor(dot, off, 64);
        float sq = csqi + csq[j] - 2.f * dot;
        float dist = sqrtf(fmaxf(sq, 0.f) + EPSF);
        float w = fmaxf(0.f, 1.f - dist);
        float scale = 0.1f * w / (dist + EPSF);
#pragma unroll
        for (int m = 0; m < 8; ++m) racc[m] += scale * (cil[m] - cjl[m]);
    }
#pragma unroll
    for (int m = 0; m < 8; ++m) atomicAdd(&rep[lane * 8 + m], racc[m]);
    __syncthreads();
    const float invw = 1.0f / (sum_w[i] + EPSF);
    for (int d = tid; d < 512; d += 256) {
        float nc = WS[i * 512 + d] * invw;
        float upd = nc - ci[d] + rep[d];
        float mn = 0.9f * Mom[i * 512 + d] + 0.1f * upd;
        outM[i * 512 + d] = mn;
        outC[i * 512 + d] = ci[d] + 0.1f * mn;
    }
}

extern "C" void kernel_launch(void* const* d_in, const int* in_sizes, int n_in,
                              void* d_out, int out_size, void* d_ws, size_t ws_size,
                              hipStream_t stream) {
    const float* X = (const float*)d_in[0];      // (32768, 512)
    const float* C = (const float*)d_in[1];      // (512, 512)
    const float* M = (const float*)d_in[2];      // (512, 512)
    float* out = (float*)d_out;
    float* assign = out;                          // 32768*512
    float* outC = out + 16777216;                 // 512*512
    float* outM = outC + 262144;                  // 512*512

    char* wsb = (char*)d_ws;
    const size_t MB = 1024ull * 1024ull;
    float* WS = (float*)wsb;                            // 1 MB (fallback only)
    float* sum_w = (float*)(wsb + 1 * MB);              // 2 KB
    float* rsum = (float*)(wsb + 1 * MB + 2048);        // 2 KB
    float* csq = (float*)(wsb + 1 * MB + 4096);         // 2 KB
    ushort* Chl = (ushort*)(wsb + 2 * MB);              // 1 MB (512 x 1024 bf16)
    float* S = (float*)(wsb + 3 * MB);                  // 1 MB
    float* WSp = (float*)(wsb + 4 * MB);                // 32 MB (z=32)
    ushort* Xh = (ushort*)(wsb + 36 * MB);              // 32 MB (bf16 hi of X)
    ushort* Abf = (ushort*)(wsb + 100 * MB);            // 32 MB
    const size_t NEED = 132 * MB;                       // proven available

    if (ws_size >= NEED) {
        csqc_v3<<<128, 256, 0, stream>>>(C, csq, Chl, sum_w, rsum);
        logsm<<<512, 512, 0, stream>>>(X, Chl, csq, assign, Abf, Xh, sum_w);
        wsum_gram<<<528, 256, 0, stream>>>(Abf, Xh, WSp, Chl, csq, S, rsum);
        apply_update<<<512, 256, 0, stream>>>(C, M, S, rsum, WSp, sum_w, outC, outM);
    } else {
        hipMemsetAsync(d_ws, 0, 1 * MB + 8192, stream);
        csq_only<<<128, 256, 0, stream>>>(C, csq);
        logits_mfma<<<dim3(256, 4), 256, 0, stream>>>(X, C, csq, assign);
        softmax_rows<<<512, 256, 0, stream>>>(assign, sum_w, nullptr);
        gemm_wsum<<<dim3(8, 8, 32), 256, 0, stream>>>(assign, X, WS);
        repulse_update<<<512, 256, 0, stream>>>(C, M, csq, WS, sum_w, outC, outM);
    }
}